// Round 2
// baseline (150.948 us; speedup 1.0000x reference)
//
#include <hip/hip_runtime.h>
#include <hip/hip_bf16.h>
#include <stdint.h>

#define NB 256
#define LQ 128
#define LC 512
#define DIM 384
#define TROWS 32
#define ROW_BYTES (DIM * 4)           // 1536
#define STAGE_BYTES (TROWS * ROW_BYTES) // 49152
#define NSTAGE 20                      // 4 q-stages + 16 c-stages
#define CBP 392                        // bf16 tile pitch in shorts (784 B)

typedef __attribute__((ext_vector_type(8))) short short8;
typedef __attribute__((ext_vector_type(4))) float f4;
typedef __attribute__((ext_vector_type(2))) unsigned int u32x2;

__device__ __forceinline__ unsigned int pk2bf(float a, float b) {
  union { float f; uint32_t u; } x, y; x.f = a; y.f = b;
  uint32_t lo = (x.u + 0x7fffu + ((x.u >> 16) & 1u)) >> 16;
  uint32_t hi = (y.u + 0x7fffu + ((y.u >> 16) & 1u)) >> 16;
  return lo | (hi << 16);
}

__device__ __forceinline__ void gload16(const void* g, void* l) {
  __builtin_amdgcn_global_load_lds(
      (const __attribute__((address_space(1))) void*)g,
      (__attribute__((address_space(3))) void*)l, 16, 0, 0);
}

__device__ __forceinline__ void bar_lgkm() {
  asm volatile("s_waitcnt lgkmcnt(0)" ::: "memory");
  __builtin_amdgcn_s_barrier();
  __builtin_amdgcn_sched_barrier(0);
}

// One block per batch. 8 waves. Unified 20-stage DMA pipeline:
// stages 0..3  = q rows (32/stage), stages 4..19 = c tiles (32 rows each).
// Per stage: issue DMA for stage t+1 (raw f32, pre-swizzled source), vmcnt(6),
// A-phase (own 4 rows: pooled partials, row ss -> inv norm, raw bf16 -> s_cb),
// barrier, C-phase (q: owner waves grab A-frags to VGPRs; c: MFMA + masked
// max-fold with post-scaling by qinv*cinv), barrier.
__global__ __launch_bounds__(512, 1)
void fused_pool_late(const float* __restrict__ qtok, const float* __restrict__ ctok,
                     const int* __restrict__ qm, const int* __restrict__ cm,
                     float* __restrict__ pooled, float* __restrict__ late) {
  __shared__ float fbuf[2][TROWS * DIM];      // 98304 B (DMA double buffer, f32)
  __shared__ unsigned short s_cb[TROWS][CBP]; // 25088 B (bf16 tile for MFMA)
  __shared__ float s_qinv[LQ];
  __shared__ float s_cinv[TROWS];
  __shared__ int s_qm[LQ];
  __shared__ int s_cm[LC];
  __shared__ float s_cnt[16];
  __shared__ float s_wsum[8];

  const int b = blockIdx.x;
  const int tid = threadIdx.x;
  const int wave = tid >> 6, lane = tid & 63;
  const int rA = lane & 15, hi = lane >> 4;

  const char* qb = (const char*)(qtok + (size_t)b * LQ * DIM);
  const char* cb = (const char*)(ctok + (size_t)b * LC * DIM);

  if (tid < LQ) s_qm[tid] = qm[b * LQ + tid];
  s_cm[tid] = cm[b * LC + tid];
  __syncthreads();  // masks visible; nothing else in flight yet

  // Per-lane swizzled DMA source offsets. LDS slot n (16B chunks) within the
  // tile holds global chunk (n%96) ^ (row&7), row = n/96.  Read side applies
  // the same XOR -> bank-conflict-free b128 reads despite linear DMA dest.
  int goff[6];
#pragma unroll
  for (int j = 0; j < 6; ++j) {
    unsigned n = (unsigned)wave * 384u + (unsigned)j * 64u + (unsigned)lane;
    unsigned row = n / 96u, cc = n % 96u;
    goff[j] = (int)(row * ROW_BYTES + ((cc ^ (row & 7u)) << 4));
  }

  // prologue: stage 0 -> fbuf[0]
  {
    char* ldst = (char*)&fbuf[0][0] + wave * 6144;
#pragma unroll
    for (int j = 0; j < 6; ++j) gload16(qb + goff[j], ldst + j * 1024);
  }

  f4 pqa = {0.f,0.f,0.f,0.f}, pqb = {0.f,0.f,0.f,0.f};
  f4 pca = {0.f,0.f,0.f,0.f}, pcb = {0.f,0.f,0.f,0.f};
  float cq = 0.f, ccnt = 0.f;
  float rm[4] = {-1e9f, -1e9f, -1e9f, -1e9f};
  short8 A[12] = {};

  for (int t = 0; t < NSTAGE; ++t) {
    const int cur = t & 1;
    if (t + 1 < NSTAGE) {
      const char* base = (t + 1 < 4) ? (qb + (size_t)(t + 1) * STAGE_BYTES)
                                     : (cb + (size_t)(t + 1 - 4) * STAGE_BYTES);
      char* ldst = (char*)&fbuf[cur ^ 1][0] + wave * 6144;
#pragma unroll
      for (int j = 0; j < 6; ++j) gload16(base + goff[j], ldst + j * 1024);
      asm volatile("s_waitcnt vmcnt(6)" ::: "memory");  // stage t landed; t+1 stays in flight
    } else {
      asm volatile("s_waitcnt vmcnt(0)" ::: "memory");
    }
    __builtin_amdgcn_sched_barrier(0);

    // ---- A phase: this wave's own 4 rows of fbuf[cur] (it DMA'd them itself)
    const char* fb = (const char*)&fbuf[cur][0];
    const bool isq = (t < 4);
#pragma unroll
    for (int r0 = 0; r0 < 4; ++r0) {
      const int lrow = wave * 4 + r0;
      const int k7 = lrow & 7;
      const f4 va = *(const f4*)(fb + lrow * ROW_BYTES + ((lane ^ k7) << 4));
      f4 vb = {0.f,0.f,0.f,0.f};
      if (lane < 32) vb = *(const f4*)(fb + lrow * ROW_BYTES + (((64 + lane) ^ k7) << 4));
      float ss = va.x*va.x + va.y*va.y + va.z*va.z + va.w*va.w
               + vb.x*vb.x + vb.y*vb.y + vb.z*vb.z + vb.w*vb.w;
#pragma unroll
      for (int o = 32; o; o >>= 1) ss += __shfl_xor(ss, o);
      const float inv = 1.0f / fmaxf(sqrtf(ss), 1e-12f);
      const int mk = isq ? s_qm[t * 32 + lrow] : s_cm[(t - 4) * 32 + lrow];
      const float fm = (float)mk;
      if (isq) {
        pqa += va * fm; pqb += vb * fm; cq += fm;
        if (lane == 0) s_qinv[t * 32 + lrow] = inv;
      } else {
        pca += va * fm; pcb += vb * fm; ccnt += fm;
        if (lane == 0) s_cinv[lrow] = inv;
      }
      u32x2 w0; w0[0] = pk2bf(va.x, va.y); w0[1] = pk2bf(va.z, va.w);
      *(u32x2*)&s_cb[lrow][4 * lane] = w0;
      if (lane < 32) {
        u32x2 w1; w1[0] = pk2bf(vb.x, vb.y); w1[1] = pk2bf(vb.z, vb.w);
        *(u32x2*)&s_cb[lrow][256 + 4 * lane] = w1;
      }
    }
    bar_lgkm();  // s_cb / s_*inv visible to all waves; vmcnt NOT drained

    // ---- C phase
    if (isq) {
      if ((wave >> 1) == t) {  // waves 2t, 2t+1 own rows [32t, 32t+32)
        const int lbase = (wave & 1) * 16 + rA;
#pragma unroll
        for (int kk = 0; kk < 12; ++kk)
          A[kk] = *(const short8*)&s_cb[lbase][kk * 32 + hi * 8];
        asm volatile("s_waitcnt lgkmcnt(0)" ::: "memory");  // A[] settled before s_cb reuse
        __builtin_amdgcn_sched_barrier(0);
      }
    } else {
      f4 acc0 = {0.f,0.f,0.f,0.f}, acc1 = {0.f,0.f,0.f,0.f};
#pragma unroll
      for (int kk = 0; kk < 12; ++kk) {
        const short8 b0 = *(const short8*)&s_cb[rA][kk * 32 + hi * 8];
        const short8 b1 = *(const short8*)&s_cb[rA + 16][kk * 32 + hi * 8];
        acc0 = __builtin_amdgcn_mfma_f32_16x16x32_bf16(A[kk], b0, acc0, 0, 0, 0);
        acc1 = __builtin_amdgcn_mfma_f32_16x16x32_bf16(A[kk], b1, acc1, 0, 0, 0);
      }
      const int tb = (t - 4) * 32;
      const bool v0 = s_cm[tb + rA] != 0;
      const bool v1 = s_cm[tb + rA + 16] != 0;
      const float ci0 = s_cinv[rA], ci1 = s_cinv[rA + 16];
#pragma unroll
      for (int r = 0; r < 4; ++r) {
        const float qi = s_qinv[wave * 16 + hi * 4 + r];
        const float a0 = v0 ? acc0[r] * (qi * ci0) : -1e9f;
        const float a1 = v1 ? acc1[r] * (qi * ci1) : -1e9f;
        rm[r] = fmaxf(rm[r], fmaxf(a0, a1));
      }
    }
    bar_lgkm();
  }

  // ---- final reductions (reuse fbuf as [16][384] partial store)
  float* red = (float*)&fbuf[0][0];
  *(f4*)&red[wave * DIM + 4 * lane] = pqa;
  if (lane < 32) *(f4*)&red[wave * DIM + 256 + 4 * lane] = pqb;
  *(f4*)&red[(8 + wave) * DIM + 4 * lane] = pca;
  if (lane < 32) *(f4*)&red[(8 + wave) * DIM + 256 + 4 * lane] = pcb;
  if (lane == 0) { s_cnt[wave] = cq; s_cnt[8 + wave] = ccnt; }

#pragma unroll
  for (int r = 0; r < 4; ++r) {
#pragma unroll
    for (int o = 1; o < 16; o <<= 1) rm[r] = fmaxf(rm[r], __shfl_xor(rm[r], o));
  }
  float ps = 0.f;
  if (rA == 0) {
    const int rowb = wave * 16 + hi * 4;
#pragma unroll
    for (int r = 0; r < 4; ++r) ps += s_qm[rowb + r] ? rm[r] : 0.f;
  }
#pragma unroll
  for (int o = 32; o; o >>= 1) ps += __shfl_xor(ps, o);
  if (lane == 0) s_wsum[wave] = ps;
  __syncthreads();

  if (tid < DIM) {
    float sq = 0.f, sc = 0.f, nq = 0.f, nc = 0.f;
#pragma unroll
    for (int w = 0; w < 8; ++w) {
      sq += red[w * DIM + tid];
      sc += red[(8 + w) * DIM + tid];
      nq += s_cnt[w];
      nc += s_cnt[8 + w];
    }
    pooled[b * DIM + tid] = sq / fmaxf(nq, 1e-9f);
    pooled[(NB + b) * DIM + tid] = sc / fmaxf(nc, 1e-9f);
  }
  if (tid == 0) {
    float tot = 0.f;
#pragma unroll
    for (int w = 0; w < 8; ++w) tot += s_wsum[w];
    late[b] = tot;
  }
}

// 4 pooled rows per block (128 blocks): 8x fewer W1/W2 reads than 1 row/block.
__global__ __launch_bounds__(DIM)
void mlp_kernel(const float* __restrict__ pooled, const float* __restrict__ W1,
                const float* __restrict__ b1, const float* __restrict__ W2,
                const float* __restrict__ b2, float* __restrict__ emb) {
  __shared__ float s_in[4][DIM];
  __shared__ float s_h[4][DIM];
  __shared__ float s_red[4][6];
  const int r0 = blockIdx.x * 4;
  const int d = threadIdx.x;
#pragma unroll
  for (int r = 0; r < 4; ++r) s_in[r][d] = pooled[(size_t)(r0 + r) * DIM + d];
  __syncthreads();
  float acc[4] = {b1[d], b1[d], b1[d], b1[d]};
#pragma unroll 8
  for (int k = 0; k < DIM; ++k) {
    const float w = W1[k * DIM + d];
#pragma unroll
    for (int r = 0; r < 4; ++r) acc[r] = fmaf(s_in[r][k], w, acc[r]);
  }
#pragma unroll
  for (int r = 0; r < 4; ++r) s_h[r][d] = fmaxf(acc[r], 0.f);
  __syncthreads();
  float p[4] = {b2[d], b2[d], b2[d], b2[d]};
#pragma unroll 8
  for (int k = 0; k < DIM; ++k) {
    const float w = W2[k * DIM + d];
#pragma unroll
    for (int r = 0; r < 4; ++r) p[r] = fmaf(s_h[r][k], w, p[r]);
  }
#pragma unroll
  for (int r = 0; r < 4; ++r) {
    float ss = p[r] * p[r];
#pragma unroll
    for (int o = 32; o; o >>= 1) ss += __shfl_xor(ss, o);
    if ((d & 63) == 0) s_red[r][d >> 6] = ss;
  }
  __syncthreads();
#pragma unroll
  for (int r = 0; r < 4; ++r) {
    float tot = 0.f;
#pragma unroll
    for (int w = 0; w < 6; ++w) tot += s_red[r][w];
    emb[(size_t)(r0 + r) * DIM + d] = p[r] * (1.0f / fmaxf(sqrtf(tot), 1e-12f));
  }
}

// 8 q rows per block (32 blocks): c_emb traffic 12.6 MB instead of 100 MB.
__global__ __launch_bounds__(NB)
void contrast_kernel(const float* __restrict__ emb, float* __restrict__ out0) {
  __shared__ float s_q[8][DIM];
  const int i0 = blockIdx.x * 8;
  const int j = threadIdx.x;
  for (int tt = j; tt < 8 * DIM; tt += NB) s_q[tt / DIM][tt % DIM] = emb[(size_t)i0 * DIM + tt];
  __syncthreads();
  const float* ce = emb + (size_t)(NB + j) * DIM;
  float acc[8] = {0.f,0.f,0.f,0.f,0.f,0.f,0.f,0.f};
#pragma unroll 8
  for (int k = 0; k < DIM; ++k) {
    const float c = ce[k];
#pragma unroll
    for (int r = 0; r < 8; ++r) acc[r] = fmaf(s_q[r][k], c, acc[r]);
  }
#pragma unroll
  for (int r = 0; r < 8; ++r) out0[(size_t)(i0 + r) * NB + j] = acc[r] / 0.07f;
}

extern "C" void kernel_launch(void* const* d_in, const int* in_sizes, int n_in,
                              void* d_out, int out_size, void* d_ws, size_t ws_size,
                              hipStream_t stream) {
  const float* qtok = (const float*)d_in[0];
  const float* ctok = (const float*)d_in[1];
  const int*   qmm  = (const int*)d_in[2];
  const int*   cmm  = (const int*)d_in[3];
  const float* W1   = (const float*)d_in[4];
  const float* b1   = (const float*)d_in[5];
  const float* W2   = (const float*)d_in[6];
  const float* b2   = (const float*)d_in[7];

  float* out0 = (float*)d_out;            // [NB*NB]
  float* late = out0 + NB * NB;           // [NB]
  float* pooled = (float*)d_ws;           // [2*NB][DIM]
  float* emb    = pooled + 2 * NB * DIM;  // [2*NB][DIM]

  hipLaunchKernelGGL(fused_pool_late, dim3(NB), dim3(512), 0, stream,
                     qtok, ctok, qmm, cmm, pooled, late);
  hipLaunchKernelGGL(mlp_kernel, dim3(NB / 2), dim3(DIM), 0, stream,
                     pooled, W1, b1, W2, b2, emb);
  hipLaunchKernelGGL(contrast_kernel, dim3(NB / 8), dim3(NB), 0, stream, emb, out0);
}